// Round 2
// baseline (84.501 us; speedup 1.0000x reference)
//
#include <hip/hip_runtime.h>
#include <math.h>

#define BB 16
#define TT 8
#define CC 64
#define PP 2048
#define NROWS (BB * TT * CC)            // 8192
#define TOTAL_INV (1.0f / 16777216.0f)  // 1 / (B*T*C*P)

// ---------------------------------------------------------------------------
// Mask-dtype classifier: the harness's bool-handling is undocumented, so we
// detect the on-device representation from byte statistics of the first
// 64 KiB (safe to read under every dtype hypothesis: buffer >= N bytes).
//   u8 bool  : ~10%  of bytes == 0x01           -> mode 0
//   bf16 1.0 : bytes {0x80,0x3F}; ~5%  == 0x3F  -> mode 1
//   f32  1.0 : bytes {0,0,0x80,0x3F}; ~2.5%==0x3F -> mode 2
//   i32  1   : bytes {1,0,0,0}; ~2.5% == 0x01   -> mode 3
// ---------------------------------------------------------------------------
__global__ __launch_bounds__(256) void mask_classify_kernel(
    const unsigned char* __restrict__ mask, int* __restrict__ flag)
{
    __shared__ int sc1, sc3f;
    if (threadIdx.x == 0) { sc1 = 0; sc3f = 0; }
    __syncthreads();
    int c1 = 0, c3f = 0;
    const uint4* m4 = (const uint4*)mask;
    for (int i = threadIdx.x; i < 4096; i += 256) {  // 4096 * 16 B = 64 KiB
        const uint4 v = m4[i];
        const unsigned int w[4] = {v.x, v.y, v.z, v.w};
        #pragma unroll
        for (int j = 0; j < 4; ++j) {
            #pragma unroll
            for (int b = 0; b < 4; ++b) {
                const unsigned int byte = (w[j] >> (8 * b)) & 0xffu;
                c1  += (byte == 0x01u);
                c3f += (byte == 0x3fu);
            }
        }
    }
    atomicAdd(&sc1, c1);
    atomicAdd(&sc3f, c3f);
    __syncthreads();
    if (threadIdx.x == 0) {
        int f = 0;                 // default: u8 bool
        if      (sc1  > 4000) f = 0;   // ~6554 expected for u8
        else if (sc3f > 2400) f = 1;   // ~3277 expected for bf16
        else if (sc3f >  800) f = 2;   // ~1638 expected for f32
        else if (sc1  >  800) f = 3;   // ~1638 expected for i32
        *flag = f;
    }
}

template <int MODE>
__device__ __forceinline__ void load_mf(const unsigned char* __restrict__ mask,
                                        size_t idx, float mf[4])
{
    if (MODE == 0) {
        const unsigned int mv = *(const unsigned int*)(mask + idx);
        #pragma unroll
        for (int k = 0; k < 4; ++k) mf[k] = ((mv >> (8 * k)) & 0xffu) ? 1.0f : 0.0f;
    } else if (MODE == 1) {
        const ushort4 mv = *(const ushort4*)((const unsigned short*)mask + idx);
        mf[0] = mv.x ? 1.0f : 0.0f; mf[1] = mv.y ? 1.0f : 0.0f;
        mf[2] = mv.z ? 1.0f : 0.0f; mf[3] = mv.w ? 1.0f : 0.0f;
    } else if (MODE == 2) {
        const float4 mv = *(const float4*)((const float*)mask + idx);
        mf[0] = mv.x != 0.f ? 1.0f : 0.0f; mf[1] = mv.y != 0.f ? 1.0f : 0.0f;
        mf[2] = mv.z != 0.f ? 1.0f : 0.0f; mf[3] = mv.w != 0.f ? 1.0f : 0.0f;
    } else {
        const int4 mv = *(const int4*)((const int*)mask + idx);
        mf[0] = mv.x ? 1.0f : 0.0f; mf[1] = mv.y ? 1.0f : 0.0f;
        mf[2] = mv.z ? 1.0f : 0.0f; mf[3] = mv.w ? 1.0f : 0.0f;
    }
}

template <int MODE>
__device__ __forceinline__ void row_body(
    const float* __restrict__ x, const float* __restrict__ attn,
    const float* __restrict__ noise, const unsigned char* __restrict__ mask,
    const int* __restrict__ pP1, const int* __restrict__ pP2,
    const int* __restrict__ pP3,
    const float* __restrict__ lds0, const float* __restrict__ lds1,
    const float* __restrict__ lds2,
    size_t rowbase, int tid, float& s0, float& s1, float& s2, float& s3)
{
    #pragma unroll
    for (int j = 0; j < 2; ++j) {
        const int p = j * 1024 + (tid << 2);
        const float4 xv = *(const float4*)(x + rowbase + p);
        const float4 av = *(const float4*)(attn + rowbase + p);
        const float4 nv = *(const float4*)(noise + rowbase + p);
        float mf[4];
        load_mf<MODE>(mask, rowbase + p, mf);
        const int4 q1 = *(const int4*)(pP1 + p);
        const int4 q2 = *(const int4*)(pP2 + p);
        const int4 q3 = *(const int4*)(pP3 + p);

        const float xs[4] = {xv.x, xv.y, xv.z, xv.w};
        const float as[4] = {av.x, av.y, av.z, av.w};
        const float ns[4] = {nv.x, nv.y, nv.z, nv.w};
        const int q1s[4]  = {q1.x, q1.y, q1.z, q1.w};
        const int q2s[4]  = {q2.x, q2.y, q2.z, q2.w};
        const int q3s[4]  = {q3.x, q3.y, q3.z, q3.w};

        #pragma unroll
        for (int k = 0; k < 4; ++k) {
            const float a  = as[k];
            const float xk = xs[k];
            const float d0 = ns[k] * mf[k];   // x - x_pos = -noise where mask
            s0 += a * d0 * d0;
            const float d1 = xk - lds0[q1s[k]];
            s1 += a * d1 * d1;
            const float d2 = xk - lds1[q2s[k]];
            s2 += a * d2 * d2;
            const float d3 = xk - lds2[q3s[k]];
            s3 += a * d3 * d3;
        }
    }
}

// One block per output row (b,t,c). Stage the 3 permuted source rows in LDS,
// stream x/attn/noise/mask coalesced, accumulate 4 partial sums per block.
__global__ __launch_bounds__(256) void attn_loss_row_kernel(
    const float* __restrict__ x, const float* __restrict__ attn,
    const float* __restrict__ noise, const unsigned char* __restrict__ mask,
    const int* __restrict__ pB1, const int* __restrict__ pT1,
    const int* __restrict__ pC1, const int* __restrict__ pP1,
    const int* __restrict__ pB2, const int* __restrict__ pT2,
    const int* __restrict__ pC2, const int* __restrict__ pP2,
    const int* __restrict__ pB3, const int* __restrict__ pT3,
    const int* __restrict__ pC3, const int* __restrict__ pP3,
    const int* __restrict__ mask_flag,
    float4* __restrict__ partial)
{
    __shared__ float lds0[PP];
    __shared__ float lds1[PP];
    __shared__ float lds2[PP];
    __shared__ float red[4][4];

    const int r   = blockIdx.x;
    const int b   = r / (TT * CC);
    const int t   = (r / CC) % TT;
    const int c   = r % CC;
    const int tid = threadIdx.x;

    const size_t src0 = ((size_t)((pB1[b] * TT + pT1[t]) * CC + pC1[c])) * PP;
    const size_t src1 = ((size_t)((pB2[b] * TT + pT2[t]) * CC + pC2[c])) * PP;
    const size_t src2 = ((size_t)((pB3[b] * TT + pT3[t]) * CC + pC3[c])) * PP;

    #pragma unroll
    for (int j = 0; j < 2; ++j) {
        const int off = j * 1024 + (tid << 2);
        *(float4*)&lds0[off] = *(const float4*)(x + src0 + off);
        *(float4*)&lds1[off] = *(const float4*)(x + src1 + off);
        *(float4*)&lds2[off] = *(const float4*)(x + src2 + off);
    }
    __syncthreads();

    const size_t rowbase = (size_t)r * PP;
    float s0 = 0.f, s1 = 0.f, s2 = 0.f, s3 = 0.f;

    const int f = *mask_flag;  // wave-uniform
    switch (f) {
        case 1:  row_body<1>(x, attn, noise, mask, pP1, pP2, pP3,
                             lds0, lds1, lds2, rowbase, tid, s0, s1, s2, s3); break;
        case 2:  row_body<2>(x, attn, noise, mask, pP1, pP2, pP3,
                             lds0, lds1, lds2, rowbase, tid, s0, s1, s2, s3); break;
        case 3:  row_body<3>(x, attn, noise, mask, pP1, pP2, pP3,
                             lds0, lds1, lds2, rowbase, tid, s0, s1, s2, s3); break;
        default: row_body<0>(x, attn, noise, mask, pP1, pP2, pP3,
                             lds0, lds1, lds2, rowbase, tid, s0, s1, s2, s3); break;
    }

    #pragma unroll
    for (int off = 32; off; off >>= 1) {
        s0 += __shfl_down(s0, off, 64);
        s1 += __shfl_down(s1, off, 64);
        s2 += __shfl_down(s2, off, 64);
        s3 += __shfl_down(s3, off, 64);
    }
    const int wave = tid >> 6;
    const int lane = tid & 63;
    if (lane == 0) {
        red[0][wave] = s0; red[1][wave] = s1;
        red[2][wave] = s2; red[3][wave] = s3;
    }
    __syncthreads();
    if (tid == 0) {
        float4 out;
        out.x = red[0][0] + red[0][1] + red[0][2] + red[0][3];
        out.y = red[1][0] + red[1][1] + red[1][2] + red[1][3];
        out.z = red[2][0] + red[2][1] + red[2][2] + red[2][3];
        out.w = red[3][0] + red[3][1] + red[3][2] + red[3][3];
        partial[r] = out;
    }
}

__global__ __launch_bounds__(1024) void attn_loss_final_kernel(
    const float4* __restrict__ partial, float* __restrict__ out)
{
    const int tid = threadIdx.x;
    float s0 = 0.f, s1 = 0.f, s2 = 0.f, s3 = 0.f;
    for (int i = tid; i < NROWS; i += 1024) {
        const float4 v = partial[i];
        s0 += v.x; s1 += v.y; s2 += v.z; s3 += v.w;
    }
    #pragma unroll
    for (int off = 32; off; off >>= 1) {
        s0 += __shfl_down(s0, off, 64);
        s1 += __shfl_down(s1, off, 64);
        s2 += __shfl_down(s2, off, 64);
        s3 += __shfl_down(s3, off, 64);
    }
    __shared__ float red[4][16];
    const int wave = tid >> 6;
    const int lane = tid & 63;
    if (lane == 0) {
        red[0][wave] = s0; red[1][wave] = s1;
        red[2][wave] = s2; red[3][wave] = s3;
    }
    __syncthreads();
    if (tid == 0) {
        float lp = 0.f, l1 = 0.f, l2 = 0.f, l3 = 0.f;
        #pragma unroll
        for (int w = 0; w < 16; ++w) {
            lp += red[0][w]; l1 += red[1][w];
            l2 += red[2][w]; l3 += red[3][w];
        }
        lp *= TOTAL_INV; l1 *= TOTAL_INV; l2 *= TOTAL_INV; l3 *= TOTAL_INV;
        const float m   = fmaxf(l1, fmaxf(l2, l3));
        const float lse = m + logf(expf(l1 - m) + expf(l2 - m) + expf(l3 - m));
        out[0] = lse - lp;
    }
}

extern "C" void kernel_launch(void* const* d_in, const int* in_sizes, int n_in,
                              void* d_out, int out_size, void* d_ws, size_t ws_size,
                              hipStream_t stream) {
    const float* x            = (const float*)d_in[0];
    const float* attn         = (const float*)d_in[1];
    const float* noise        = (const float*)d_in[2];
    const unsigned char* mask = (const unsigned char*)d_in[3];
    const int* pB1 = (const int*)d_in[4];
    const int* pT1 = (const int*)d_in[5];
    const int* pC1 = (const int*)d_in[6];
    const int* pP1 = (const int*)d_in[7];
    const int* pB2 = (const int*)d_in[8];
    const int* pT2 = (const int*)d_in[9];
    const int* pC2 = (const int*)d_in[10];
    const int* pP2 = (const int*)d_in[11];
    const int* pB3 = (const int*)d_in[12];
    const int* pT3 = (const int*)d_in[13];
    const int* pC3 = (const int*)d_in[14];
    const int* pP3 = (const int*)d_in[15];

    float4* partial = (float4*)d_ws;                         // 128 KiB
    int* mask_flag  = (int*)((char*)d_ws + NROWS * 16);      // 4 B after partials

    mask_classify_kernel<<<1, 256, 0, stream>>>(mask, mask_flag);
    attn_loss_row_kernel<<<NROWS, 256, 0, stream>>>(
        x, attn, noise, mask,
        pB1, pT1, pC1, pP1, pB2, pT2, pC2, pP2, pB3, pT3, pC3, pP3,
        mask_flag, partial);
    attn_loss_final_kernel<<<1, 1024, 0, stream>>>(partial, (float*)d_out);
}

// Round 3
// 83.562 us; speedup vs baseline: 1.0112x; 1.0112x over previous
//
#include <hip/hip_runtime.h>
#include <math.h>

#define BB 16
#define TT 8
#define CC 64
#define PP 2048
#define NROWS (BB * TT * CC)            // 8192
#define TOTAL_INV (1.0f / 16777216.0f)  // 1 / (B*T*C*P)

// ---------------------------------------------------------------------------
// Async global->LDS staging (width 16). LDS dest is wave-uniform base +
// lane*16B; our linear segment layout matches that contract exactly.
// ---------------------------------------------------------------------------
typedef __attribute__((address_space(1))) const void* as1_cvoid;
typedef __attribute__((address_space(3))) void* as3_void;

__device__ __forceinline__ void stage16(const float* g, float* l) {
    __builtin_amdgcn_global_load_lds((as1_cvoid)g, (as3_void)l, 16, 0, 0);
}

// ---------------------------------------------------------------------------
// Mask-dtype classifier (16 KiB scan). Byte statistics:
//   u8 bool : ~10% bytes == 0x01  (exp 1638/16384) -> mode 0
//   bf16 1.0: bytes {0x80,0x3F}   (exp 0x3F: 819)  -> mode 1
//   f32 1.0 : bytes {0,0,0x80,0x3F} (exp 0x3F: 410)-> mode 2
//   i32 1   : bytes {1,0,0,0}     (exp 0x01: 410)  -> mode 3
// ---------------------------------------------------------------------------
__global__ __launch_bounds__(256) void mask_classify_kernel(
    const unsigned char* __restrict__ mask, int* __restrict__ flag)
{
    __shared__ int sc1, sc3f;
    if (threadIdx.x == 0) { sc1 = 0; sc3f = 0; }
    __syncthreads();
    int c1 = 0, c3f = 0;
    const uint4* m4 = (const uint4*)mask;
    for (int i = threadIdx.x; i < 1024; i += 256) {  // 1024 * 16 B = 16 KiB
        const uint4 v = m4[i];
        const unsigned int w[4] = {v.x, v.y, v.z, v.w};
        #pragma unroll
        for (int j = 0; j < 4; ++j) {
            #pragma unroll
            for (int bt = 0; bt < 4; ++bt) {
                const unsigned int byte = (w[j] >> (8 * bt)) & 0xffu;
                c1  += (byte == 0x01u);
                c3f += (byte == 0x3fu);
            }
        }
    }
    atomicAdd(&sc1, c1);
    atomicAdd(&sc3f, c3f);
    __syncthreads();
    if (threadIdx.x == 0) {
        int f;
        if      (sc1  > 1000) f = 0;
        else if (sc3f >  600) f = 1;
        else if (sc3f >  200) f = 2;
        else if (sc1  >  200) f = 3;
        else                  f = 0;
        *flag = f;
    }
}

template <int MODE>
__device__ __forceinline__ void mask_load(const unsigned char* __restrict__ mask,
                                          size_t idx, float mf[4])
{
    if (MODE == 0) {
        const unsigned int mv = *(const unsigned int*)(mask + idx);
        #pragma unroll
        for (int k = 0; k < 4; ++k) mf[k] = ((mv >> (8 * k)) & 0xffu) ? 1.0f : 0.0f;
    } else if (MODE == 1) {
        const ushort4 mv = *(const ushort4*)((const unsigned short*)mask + idx);
        mf[0] = mv.x ? 1.0f : 0.0f; mf[1] = mv.y ? 1.0f : 0.0f;
        mf[2] = mv.z ? 1.0f : 0.0f; mf[3] = mv.w ? 1.0f : 0.0f;
    } else if (MODE == 2) {
        const float4 mv = *(const float4*)((const float*)mask + idx);
        mf[0] = mv.x != 0.f ? 1.0f : 0.0f; mf[1] = mv.y != 0.f ? 1.0f : 0.0f;
        mf[2] = mv.z != 0.f ? 1.0f : 0.0f; mf[3] = mv.w != 0.f ? 1.0f : 0.0f;
    } else {
        const int4 mv = *(const int4*)((const int*)mask + idx);
        mf[0] = mv.x ? 1.0f : 0.0f; mf[1] = mv.y ? 1.0f : 0.0f;
        mf[2] = mv.z ? 1.0f : 0.0f; mf[3] = mv.w ? 1.0f : 0.0f;
    }
}

// All loads for both chunks issued up-front; pos-term computed while the
// async staging + streams are in flight; one barrier; then LDS gathers.
template <int MODE>
__device__ __forceinline__ void row_body(
    const float* __restrict__ x, const float* __restrict__ attn,
    const float* __restrict__ noise, const unsigned char* __restrict__ mask,
    const int* __restrict__ pP1, const int* __restrict__ pP2,
    const int* __restrict__ pP3,
    const float* __restrict__ lds0, const float* __restrict__ lds1,
    const float* __restrict__ lds2,
    size_t rowbase, int tid, float& s0, float& s1, float& s2, float& s3)
{
    const int p0 = tid << 2;
    const int p1 = 1024 + (tid << 2);

    // --- issue everything ---
    const float4 xv0 = *(const float4*)(x + rowbase + p0);
    const float4 xv1 = *(const float4*)(x + rowbase + p1);
    const float4 av0 = *(const float4*)(attn + rowbase + p0);
    const float4 av1 = *(const float4*)(attn + rowbase + p1);
    const float4 nv0 = *(const float4*)(noise + rowbase + p0);
    const float4 nv1 = *(const float4*)(noise + rowbase + p1);
    const int4 q10 = *(const int4*)(pP1 + p0);
    const int4 q11 = *(const int4*)(pP1 + p1);
    const int4 q20 = *(const int4*)(pP2 + p0);
    const int4 q21 = *(const int4*)(pP2 + p1);
    const int4 q30 = *(const int4*)(pP3 + p0);
    const int4 q31 = *(const int4*)(pP3 + p1);
    float mf0[4], mf1[4];
    mask_load<MODE>(mask, rowbase + p0, mf0);
    mask_load<MODE>(mask, rowbase + p1, mf1);

    const float xs0[4] = {xv0.x, xv0.y, xv0.z, xv0.w};
    const float xs1[4] = {xv1.x, xv1.y, xv1.z, xv1.w};
    const float as0[4] = {av0.x, av0.y, av0.z, av0.w};
    const float as1v[4] = {av1.x, av1.y, av1.z, av1.w};
    const float ns0[4] = {nv0.x, nv0.y, nv0.z, nv0.w};
    const float ns1[4] = {nv1.x, nv1.y, nv1.z, nv1.w};
    const int q1s0[4] = {q10.x, q10.y, q10.z, q10.w};
    const int q1s1[4] = {q11.x, q11.y, q11.z, q11.w};
    const int q2s0[4] = {q20.x, q20.y, q20.z, q20.w};
    const int q2s1[4] = {q21.x, q21.y, q21.z, q21.w};
    const int q3s0[4] = {q30.x, q30.y, q30.z, q30.w};
    const int q3s1[4] = {q31.x, q31.y, q31.z, q31.w};

    // --- pos term: LDS-independent, overlaps the staging latency ---
    #pragma unroll
    for (int k = 0; k < 4; ++k) {
        const float d0a = ns0[k] * mf0[k];
        s0 += as0[k] * d0a * d0a;
        const float d0b = ns1[k] * mf1[k];
        s0 += as1v[k] * d0b * d0b;
    }

    __syncthreads();  // drains vmcnt: staging complete

    // --- gather terms ---
    #pragma unroll
    for (int k = 0; k < 4; ++k) {
        const float d1a = xs0[k] - lds0[q1s0[k]];
        s1 += as0[k] * d1a * d1a;
        const float d2a = xs0[k] - lds1[q2s0[k]];
        s2 += as0[k] * d2a * d2a;
        const float d3a = xs0[k] - lds2[q3s0[k]];
        s3 += as0[k] * d3a * d3a;
        const float d1b = xs1[k] - lds0[q1s1[k]];
        s1 += as1v[k] * d1b * d1b;
        const float d2b = xs1[k] - lds1[q2s1[k]];
        s2 += as1v[k] * d2b * d2b;
        const float d3b = xs1[k] - lds2[q3s1[k]];
        s3 += as1v[k] * d3b * d3b;
    }
}

__global__ __launch_bounds__(256) void attn_loss_row_kernel(
    const float* __restrict__ x, const float* __restrict__ attn,
    const float* __restrict__ noise, const unsigned char* __restrict__ mask,
    const int* __restrict__ pB1, const int* __restrict__ pT1,
    const int* __restrict__ pC1, const int* __restrict__ pP1,
    const int* __restrict__ pB2, const int* __restrict__ pT2,
    const int* __restrict__ pC2, const int* __restrict__ pP2,
    const int* __restrict__ pB3, const int* __restrict__ pT3,
    const int* __restrict__ pC3, const int* __restrict__ pP3,
    const int* __restrict__ mask_flag,
    float4* __restrict__ partial)
{
    __shared__ float lds0[PP];
    __shared__ float lds1[PP];
    __shared__ float lds2[PP];
    __shared__ float red[4][4];

    const int r    = blockIdx.x;
    const int b    = r / (TT * CC);
    const int t    = (r / CC) % TT;
    const int c    = r % CC;
    const int tid  = threadIdx.x;
    const int wave = tid >> 6;
    const int lane = tid & 63;

    const size_t src0 = ((size_t)((pB1[b] * TT + pT1[t]) * CC + pC1[c])) * PP;
    const size_t src1 = ((size_t)((pB2[b] * TT + pT2[t]) * CC + pC2[c])) * PP;
    const size_t src2 = ((size_t)((pB3[b] * TT + pT3[t]) * CC + pC3[c])) * PP;

    // Async stage: 8 segments of 256 floats per row; wave w owns segs w, w+4.
    // Per inst: lane i loads 16B at float-offset lane*4; LDS base wave-uniform.
    #pragma unroll
    for (int s = 0; s < 2; ++s) {
        const int seg = wave + s * 4;
        const int fo  = seg * 256 + lane * 4;
        stage16(x + src0 + fo, &lds0[seg * 256]);
        stage16(x + src1 + fo, &lds1[seg * 256]);
        stage16(x + src2 + fo, &lds2[seg * 256]);
    }

    const size_t rowbase = (size_t)r * PP;
    float s0 = 0.f, s1 = 0.f, s2 = 0.f, s3 = 0.f;

    const int f = *mask_flag;  // grid-uniform
    switch (f) {
        case 1:  row_body<1>(x, attn, noise, mask, pP1, pP2, pP3,
                             lds0, lds1, lds2, rowbase, tid, s0, s1, s2, s3); break;
        case 2:  row_body<2>(x, attn, noise, mask, pP1, pP2, pP3,
                             lds0, lds1, lds2, rowbase, tid, s0, s1, s2, s3); break;
        case 3:  row_body<3>(x, attn, noise, mask, pP1, pP2, pP3,
                             lds0, lds1, lds2, rowbase, tid, s0, s1, s2, s3); break;
        default: row_body<0>(x, attn, noise, mask, pP1, pP2, pP3,
                             lds0, lds1, lds2, rowbase, tid, s0, s1, s2, s3); break;
    }

    #pragma unroll
    for (int off = 32; off; off >>= 1) {
        s0 += __shfl_down(s0, off, 64);
        s1 += __shfl_down(s1, off, 64);
        s2 += __shfl_down(s2, off, 64);
        s3 += __shfl_down(s3, off, 64);
    }
    if (lane == 0) {
        red[0][wave] = s0; red[1][wave] = s1;
        red[2][wave] = s2; red[3][wave] = s3;
    }
    __syncthreads();
    if (tid == 0) {
        float4 out;
        out.x = red[0][0] + red[0][1] + red[0][2] + red[0][3];
        out.y = red[1][0] + red[1][1] + red[1][2] + red[1][3];
        out.z = red[2][0] + red[2][1] + red[2][2] + red[2][3];
        out.w = red[3][0] + red[3][1] + red[3][2] + red[3][3];
        partial[r] = out;
    }
}

__global__ __launch_bounds__(1024) void attn_loss_final_kernel(
    const float4* __restrict__ partial, float* __restrict__ out)
{
    const int tid = threadIdx.x;
    float s0 = 0.f, s1 = 0.f, s2 = 0.f, s3 = 0.f;
    for (int i = tid; i < NROWS; i += 1024) {
        const float4 v = partial[i];
        s0 += v.x; s1 += v.y; s2 += v.z; s3 += v.w;
    }
    #pragma unroll
    for (int off = 32; off; off >>= 1) {
        s0 += __shfl_down(s0, off, 64);
        s1 += __shfl_down(s1, off, 64);
        s2 += __shfl_down(s2, off, 64);
        s3 += __shfl_down(s3, off, 64);
    }
    __shared__ float red[4][16];
    const int wave = tid >> 6;
    const int lane = tid & 63;
    if (lane == 0) {
        red[0][wave] = s0; red[1][wave] = s1;
        red[2][wave] = s2; red[3][wave] = s3;
    }
    __syncthreads();
    if (tid == 0) {
        float lp = 0.f, l1 = 0.f, l2 = 0.f, l3 = 0.f;
        #pragma unroll
        for (int w = 0; w < 16; ++w) {
            lp += red[0][w]; l1 += red[1][w];
            l2 += red[2][w]; l3 += red[3][w];
        }
        lp *= TOTAL_INV; l1 *= TOTAL_INV; l2 *= TOTAL_INV; l3 *= TOTAL_INV;
        const float m   = fmaxf(l1, fmaxf(l2, l3));
        const float lse = m + logf(expf(l1 - m) + expf(l2 - m) + expf(l3 - m));
        out[0] = lse - lp;
    }
}

extern "C" void kernel_launch(void* const* d_in, const int* in_sizes, int n_in,
                              void* d_out, int out_size, void* d_ws, size_t ws_size,
                              hipStream_t stream) {
    const float* x            = (const float*)d_in[0];
    const float* attn         = (const float*)d_in[1];
    const float* noise        = (const float*)d_in[2];
    const unsigned char* mask = (const unsigned char*)d_in[3];
    const int* pB1 = (const int*)d_in[4];
    const int* pT1 = (const int*)d_in[5];
    const int* pC1 = (const int*)d_in[6];
    const int* pP1 = (const int*)d_in[7];
    const int* pB2 = (const int*)d_in[8];
    const int* pT2 = (const int*)d_in[9];
    const int* pC2 = (const int*)d_in[10];
    const int* pP2 = (const int*)d_in[11];
    const int* pB3 = (const int*)d_in[12];
    const int* pT3 = (const int*)d_in[13];
    const int* pC3 = (const int*)d_in[14];
    const int* pP3 = (const int*)d_in[15];

    float4* partial = (float4*)d_ws;                     // 128 KiB
    int* mask_flag  = (int*)((char*)d_ws + NROWS * 16);  // 4 B after partials

    mask_classify_kernel<<<1, 256, 0, stream>>>(mask, mask_flag);
    attn_loss_row_kernel<<<NROWS, 256, 0, stream>>>(
        x, attn, noise, mask,
        pB1, pT1, pC1, pP1, pB2, pT2, pC2, pP2, pB3, pT3, pC3, pP3,
        mask_flag, partial);
    attn_loss_final_kernel<<<1, 1024, 0, stream>>>(partial, (float*)d_out);
}